// Round 4
// baseline (542.216 us; speedup 1.0000x reference)
//
#include <hip/hip_runtime.h>

// FastVCompressor: VQ nearest-code + gather + sparsity mask.
//   keys [4,4096,1024] f32, values [4,4096,1024] f32, codebook [256,1024] f32
// out = concat(keys_c, values_c) f32.
//
// R4: bf16-split MFMA (hi/lo double-bf16, 4 MFMA per tile k-step -> fp32
//     error ~ plain fp32 chain, which passed 3x with absmax 0), fused
//     argmin + fp64 margin-recheck + gather in ONE kernel.
//   - block = 128 rows x 256 codes (all codes -> no partial combine),
//     512 threads = 8 waves, wave tile 64x64 = 16 MFMA tiles (16x16x32).
//   - frag-major LDS layouts: every ds_read/ds_write is consecutive b128
//     (conflict-free by construction).
//   - codebook pre-split to frag-major bf16 hi/lo in ws by prep kernel.
//   - rows with (best2 - best1) < 0.05 re-resolved in fp64 (exact argmin).

#define H 1024
#define NC 256
#define MT 128          // rows per block
#define THREADS 512
#define BK 32           // K per chunk = one 16x16x32 k-step
#define KSTEPS (H / BK) // 32

typedef __attribute__((ext_vector_type(8))) short bf16x8;
typedef __attribute__((ext_vector_type(4))) float f32x4;

static __device__ inline unsigned short f2bf_rne(float f) {
    unsigned u = __float_as_uint(f);
    u += 0x7FFF + ((u >> 16) & 1);   // round-to-nearest-even
    return (unsigned short)(u >> 16);
}
static __device__ inline float bf2f(unsigned short h) {
    return __uint_as_float((unsigned)h << 16);
}

// ---------------- prep: c_sq ----------------
__global__ __launch_bounds__(256) void csq_kernel(const float* __restrict__ cb,
                                                  float* __restrict__ c_sq) {
    const int b = blockIdx.x;
    const int t = threadIdx.x;
    const float4 v = *(const float4*)(cb + (size_t)b * H + 4 * t);
    float s = v.x * v.x + v.y * v.y + v.z * v.z + v.w * v.w;
    #pragma unroll
    for (int off = 32; off > 0; off >>= 1) s += __shfl_down(s, off);
    __shared__ float red[4];
    if ((t & 63) == 0) red[t >> 6] = s;
    __syncthreads();
    if (t == 0) c_sq[b] = red[0] + red[1] + red[2] + red[3];
}

// ---------------- prep: codebook -> frag-major bf16 hi/lo ----------------
// wbuf layout (shorts): idx(s,ct,h,l,j) = (((s*16+ct)*2+h)*64+l)*8 + j
//   s: k-chunk (32), ct: 16-code tile (16), h: 0=hi 1=lo, l: lane, j: 0..7
// B-frag semantics: lane l of tile ct holds B[k = s*32 + (l>>4)*8 + j]
//                                           [n = ct*16 + (l&15)]
__global__ __launch_bounds__(256) void prep_frag_kernel(const float* __restrict__ cb,
                                                        unsigned short* __restrict__ wbuf) {
    const int s = blockIdx.x;      // k-chunk
    const int t = threadIdx.x;
    const int l = t & 63;
    #pragma unroll
    for (int it = 0; it < 4; ++it) {
        const int ct = it * 4 + (t >> 6);
        const int code = ct * 16 + (l & 15);
        const int k0 = s * BK + (l >> 4) * 8;
        const float4 a = *(const float4*)(cb + (size_t)code * H + k0);
        const float4 b = *(const float4*)(cb + (size_t)code * H + k0 + 4);
        float x[8] = {a.x, a.y, a.z, a.w, b.x, b.y, b.z, b.w};
        unsigned short hi[8], lo[8];
        #pragma unroll
        for (int j = 0; j < 8; ++j) {
            hi[j] = f2bf_rne(x[j]);
            lo[j] = f2bf_rne(x[j] - bf2f(hi[j]));
        }
        const size_t base = ((((size_t)s * 16 + ct) * 2) * 64 + l) * 8;
        *(uint4*)(wbuf + base) = *(const uint4*)hi;             // h=0
        *(uint4*)(wbuf + base + 64 * 8) = *(const uint4*)lo;    // h=1
    }
}

// ---------------- fused GEMM-argmin + recheck + gather ----------------
__global__ __launch_bounds__(THREADS, 2) void argmin_gather_kernel(
    const float* __restrict__ keys, const float* __restrict__ vals,
    const float* __restrict__ cb, const unsigned short* __restrict__ wbuf,
    const float* __restrict__ c_sq, float* __restrict__ out) {
    // frag-major LDS: A: [rt(8)][h(2)][lane(64)] x 8 shorts = 16 KB
    //                 B: [ct(16)][h(2)][lane(64)] x 8 shorts = 32 KB
    __shared__ short a_sm[8 * 2 * 64 * 8];
    __shared__ short b_sm[16 * 2 * 64 * 8];
    __shared__ int fidx[MT];
    __shared__ int fflag[MT];

    const int t = threadIdx.x;
    const int lane = t & 63;
    const int w = t >> 6;           // wave 0..7
    const int g = w >> 2;           // row group 0..1 (64 rows each)
    const int cg = w & 3;           // code group 0..3 (64 codes each)
    const int tensor = blockIdx.y;
    const float* __restrict__ X = tensor ? vals : keys;
    const int row0 = blockIdx.x * MT;

    // staging assignment: A slot (rt = t>>6, l = t&63)
    const int s_rt = w;
    const int s_row = row0 + s_rt * 16 + (lane & 15);
    const int s_kq = (lane >> 4) * 8;

    f32x4 acc[4][4];
    #pragma unroll
    for (int i = 0; i < 4; ++i)
        #pragma unroll
        for (int j = 0; j < 4; ++j) acc[i][j] = (f32x4){0.f, 0.f, 0.f, 0.f};

    // prefetch chunk 0
    float4 xa0 = *(const float4*)(X + (size_t)s_row * H + s_kq);
    float4 xa1 = *(const float4*)(X + (size_t)s_row * H + s_kq + 4);
    uint4 bb[4];
    #pragma unroll
    for (int jj = 0; jj < 4; ++jj)
        bb[jj] = *(const uint4*)(wbuf + ((size_t)(t + THREADS * jj)) * 8);

    uint4* const a_u4 = (uint4*)a_sm;
    uint4* const b_u4 = (uint4*)b_sm;

    for (int s = 0; s < KSTEPS; ++s) {
        __syncthreads();   // previous compute done reading LDS
        {   // write A (convert fp32 -> hi/lo bf16), frag-major
            float x[8] = {xa0.x, xa0.y, xa0.z, xa0.w, xa1.x, xa1.y, xa1.z, xa1.w};
            unsigned short hi[8], lo[8];
            #pragma unroll
            for (int j = 0; j < 8; ++j) {
                hi[j] = f2bf_rne(x[j]);
                lo[j] = f2bf_rne(x[j] - bf2f(hi[j]));
            }
            a_u4[(s_rt * 2 + 0) * 64 + lane] = *(const uint4*)hi;
            a_u4[(s_rt * 2 + 1) * 64 + lane] = *(const uint4*)lo;
            #pragma unroll
            for (int jj = 0; jj < 4; ++jj) b_u4[t + THREADS * jj] = bb[jj];
        }
        __syncthreads();
        // prefetch next chunk
        if (s + 1 < KSTEPS) {
            const int kn = (s + 1) * BK;
            xa0 = *(const float4*)(X + (size_t)s_row * H + kn + s_kq);
            xa1 = *(const float4*)(X + (size_t)s_row * H + kn + s_kq + 4);
            #pragma unroll
            for (int jj = 0; jj < 4; ++jj)
                bb[jj] = *(const uint4*)(wbuf + ((size_t)(s + 1) * 2048 + t + THREADS * jj) * 8);
        }
        // load frags + MFMA
        bf16x8 ah[4], al[4], bh[4], bl[4];
        #pragma unroll
        for (int i = 0; i < 4; ++i) {
            const int rt = g * 4 + i;
            ah[i] = ((bf16x8*)a_sm)[(rt * 2 + 0) * 64 + lane];
            al[i] = ((bf16x8*)a_sm)[(rt * 2 + 1) * 64 + lane];
        }
        #pragma unroll
        for (int j = 0; j < 4; ++j) {
            const int ct = cg * 4 + j;
            bh[j] = ((bf16x8*)b_sm)[(ct * 2 + 0) * 64 + lane];
            bl[j] = ((bf16x8*)b_sm)[(ct * 2 + 1) * 64 + lane];
        }
        #pragma unroll
        for (int i = 0; i < 4; ++i)
            #pragma unroll
            for (int j = 0; j < 4; ++j) {
                acc[i][j] = __builtin_amdgcn_mfma_f32_16x16x32_bf16(al[i], bl[j], acc[i][j], 0, 0, 0);
                acc[i][j] = __builtin_amdgcn_mfma_f32_16x16x32_bf16(al[i], bh[j], acc[i][j], 0, 0, 0);
                acc[i][j] = __builtin_amdgcn_mfma_f32_16x16x32_bf16(ah[i], bl[j], acc[i][j], 0, 0, 0);
                acc[i][j] = __builtin_amdgcn_mfma_f32_16x16x32_bf16(ah[i], bh[j], acc[i][j], 0, 0, 0);
            }
    }

    // ---- per-row argmin with best-2 tracking ----
    float csq[4];
    #pragma unroll
    for (int j = 0; j < 4; ++j) csq[j] = c_sq[cg * 64 + j * 16 + (lane & 15)];

    __syncthreads();  // done with a_sm/b_sm; reuse as reduce scratch
    float* rv = (float*)a_sm;            // [MT][4] best val
    int* ri = (int*)(a_sm + 2 * MT * 4); // [MT][4] best idx   (offset in shorts)
    float* r2 = (float*)b_sm;            // [MT][4] second-best val

    #pragma unroll
    for (int i = 0; i < 4; ++i) {        // row tile within row group
        #pragma unroll
        for (int r = 0; r < 4; ++r) {    // C/D reg -> row = (lane>>4)*4 + r
            const int row = g * 64 + i * 16 + (lane >> 4) * 4 + r;
            float bv = csq[0] - 2.0f * acc[i][0][r];
            int bc = cg * 64 + 0 * 16 + (lane & 15);
            float b2 = 3.4e38f;
            #pragma unroll
            for (int j = 1; j < 4; ++j) {   // ascending code: strict < = first
                const float v = csq[j] - 2.0f * acc[i][j][r];
                if (v < bv) { b2 = bv; bv = v; bc = cg * 64 + j * 16 + (lane & 15); }
                else b2 = fminf(b2, v);
            }
            #pragma unroll
            for (int off = 1; off < 16; off <<= 1) {  // reduce across lane&15
                const float ov = __shfl_xor(bv, off);
                const int oc = __shfl_xor(bc, off);
                const float ov2 = __shfl_xor(b2, off);
                const float nb2 = fminf(fmaxf(bv, ov), fminf(b2, ov2));
                if (ov < bv || (ov == bv && oc < bc)) { bv = ov; bc = oc; }
                b2 = nb2;
            }
            if ((lane & 15) == 0) {
                rv[row * 4 + cg] = bv;
                ri[row * 4 + cg] = bc;
                r2[row * 4 + cg] = b2;
            }
        }
    }
    __syncthreads();
    if (t < MT) {
        float bv = rv[t * 4];
        int bc = ri[t * 4];
        float b2 = r2[t * 4];
        #pragma unroll
        for (int cgg = 1; cgg < 4; ++cgg) {   // ascending code groups
            const float v = rv[t * 4 + cgg];
            const int c = ri[t * 4 + cgg];
            const float v2 = r2[t * 4 + cgg];
            const float nb2 = fminf(fmaxf(bv, v), fminf(b2, v2));
            if (v < bv || (v == bv && c < bc)) { bv = v; bc = c; }
            b2 = nb2;
        }
        fidx[t] = bc;
        fflag[t] = (b2 - bv < 0.05f) ? 1 : 0;   // margin below approx-error guard
    }
    __syncthreads();

    // ---- fp64 exact recheck of flagged rows (rare) ----
    if (w == 0) {
        for (int row = 0; row < MT; ++row) {
            if (!fflag[row]) continue;
            const float* xr = X + (size_t)(row0 + row) * H;
            double d[4] = {0.0, 0.0, 0.0, 0.0};   // codes lane*4 .. lane*4+3
            for (int k = 0; k < H; ++k) {
                const double xv = (double)xr[k];
                #pragma unroll
                for (int c4 = 0; c4 < 4; ++c4) {
                    const double diff = xv - (double)cb[(size_t)(lane * 4 + c4) * H + k];
                    d[c4] += diff * diff;
                }
            }
            double bv = d[0];
            int bc = lane * 4;
            #pragma unroll
            for (int c4 = 1; c4 < 4; ++c4)
                if (d[c4] < bv) { bv = d[c4]; bc = lane * 4 + c4; }  // ascending
            #pragma unroll
            for (int off = 1; off < 64; off <<= 1) {
                const double ov = __shfl_xor(bv, off);
                const int oc = __shfl_xor(bc, off);
                if (ov < bv || (ov == bv && oc < bc)) { bv = ov; bc = oc; }
            }
            if (lane == 0) fidx[row] = bc;
        }
    }
    __syncthreads();

    // ---- masked gather: each wave writes 16 rows ----
    for (int rr = 0; rr < 16; ++rr) {
        const int row = w * 16 + rr;
        const int bi = fidx[row];
        const float m = (c_sq[bi] > 0.01f) ? 1.0f : 0.0f;
        const float4* __restrict__ src = (const float4*)(cb + (size_t)bi * H);
        float4* __restrict__ dst =
            (float4*)(out + ((size_t)tensor * (gridDim.x * MT) + row0 + row) * H);
        #pragma unroll
        for (int j = 0; j < 4; ++j) {
            float4 v = src[j * 64 + lane];
            v.x *= m; v.y *= m; v.z *= m; v.w *= m;
            dst[j * 64 + lane] = v;
        }
    }
}

extern "C" void kernel_launch(void* const* d_in, const int* in_sizes, int n_in,
                              void* d_out, int out_size, void* d_ws, size_t ws_size,
                              hipStream_t stream) {
    const float* keys = (const float*)d_in[0];
    const float* vals = (const float*)d_in[1];
    const float* cb   = (const float*)d_in[2];
    float* out = (float*)d_out;

    // ws layout: c_sq[256] f32 | wbuf[512K shorts = 1 MB]
    float* c_sq = (float*)d_ws;
    unsigned short* wbuf = (unsigned short*)(c_sq + NC);

    const int rows = in_sizes[0] / H;  // 16384 per tensor

    csq_kernel<<<NC, 256, 0, stream>>>(cb, c_sq);
    prep_frag_kernel<<<KSTEPS, 256, 0, stream>>>(cb, wbuf);
    dim3 g(rows / MT, 2);
    argmin_gather_kernel<<<g, THREADS, 0, stream>>>(keys, vals, cb, wbuf, c_sq, out);
}

// Round 5
// 372.679 us; speedup vs baseline: 1.4549x; 1.4549x over previous
//
#include <hip/hip_runtime.h>

// FastVCompressor: VQ nearest-code + gather + sparsity mask.
//   keys [4,4096,1024] f32, values [4,4096,1024] f32, codebook [256,1024] f32
// out = concat(keys_c, values_c) f32.
//
// R5: bf16 hi/lo split MFMA (3 MFMA/tile, ll dropped; margin 0.15 + exact
//     fp64 recheck kernel covers worst-case split error ~0.04).
//   - main: MT=64 rows, 256 thr (4 waves), wave = 4 rt x 4 ct (64 AGPR acc).
//     grid 512 = 2 blocks/CU. ONE barrier/step: double-buffered LDS,
//     B staged via global_load_lds width=16 from pre-split frag-major wbuf,
//     A staged via reg prefetch + in-reg hi/lo convert.
//   - recheck: separate kernel, fp64 exact argmin of margin-flagged rows
//     (ballot-skip; coalesced via k-major wt transpose).
//   - gather: separate, one wave per row.

#define H 1024
#define NC 256
#define MT 64
#define THREADS 256
#define BK 32
#define KSTEPS (H / BK)   // 32

typedef __attribute__((ext_vector_type(8))) short bf16x8;
typedef __attribute__((ext_vector_type(4))) float f32x4;

static __device__ inline unsigned short f2bf_rne(float f) {
    unsigned u = __float_as_uint(f);
    u += 0x7FFF + ((u >> 16) & 1);
    return (unsigned short)(u >> 16);
}
static __device__ inline float bf2f(unsigned short h) {
    return __uint_as_float((unsigned)h << 16);
}
static __device__ inline void gl_lds16(const void* g, void* l) {
    __builtin_amdgcn_global_load_lds(
        (const __attribute__((address_space(1))) unsigned int*)g,
        (__attribute__((address_space(3))) unsigned int*)l, 16, 0, 0);
}

// ---------------- prep: c_sq + k-major fp32 transpose (for fp64 recheck) ----
__global__ __launch_bounds__(256) void prep_kernel(const float* __restrict__ cb,
                                                   float* __restrict__ c_sq,
                                                   float* __restrict__ wt) {
    const int b = blockIdx.x;
    const int t = threadIdx.x;
    const float4 v = *(const float4*)(cb + (size_t)b * H + 4 * t);
    wt[(size_t)(4 * t + 0) * NC + b] = v.x;
    wt[(size_t)(4 * t + 1) * NC + b] = v.y;
    wt[(size_t)(4 * t + 2) * NC + b] = v.z;
    wt[(size_t)(4 * t + 3) * NC + b] = v.w;
    float s = v.x * v.x + v.y * v.y + v.z * v.z + v.w * v.w;
    #pragma unroll
    for (int off = 32; off > 0; off >>= 1) s += __shfl_down(s, off);
    __shared__ float red[4];
    if ((t & 63) == 0) red[t >> 6] = s;
    __syncthreads();
    if (t == 0) c_sq[b] = red[0] + red[1] + red[2] + red[3];
}

// ---------------- prep: codebook -> frag-major bf16 hi/lo ----------------
// wbuf uint4 index within slice s: (ct*2 + h)*64 + lane ; slice = 2048 uint4.
// B-frag: lane l of tile ct holds B[k = s*32 + (l>>4)*8 + j][n = ct*16 + (l&15)]
__global__ __launch_bounds__(256) void prep_frag_kernel(const float* __restrict__ cb,
                                                        unsigned short* __restrict__ wbuf) {
    const int s = blockIdx.x;
    const int t = threadIdx.x;
    const int l = t & 63;
    #pragma unroll
    for (int it = 0; it < 4; ++it) {
        const int ct = it * 4 + (t >> 6);
        const int code = ct * 16 + (l & 15);
        const int k0 = s * BK + (l >> 4) * 8;
        const float4 a = *(const float4*)(cb + (size_t)code * H + k0);
        const float4 b = *(const float4*)(cb + (size_t)code * H + k0 + 4);
        float x[8] = {a.x, a.y, a.z, a.w, b.x, b.y, b.z, b.w};
        unsigned short hi[8], lo[8];
        #pragma unroll
        for (int j = 0; j < 8; ++j) {
            hi[j] = f2bf_rne(x[j]);
            lo[j] = f2bf_rne(x[j] - bf2f(hi[j]));
        }
        const size_t base = ((((size_t)s * 16 + ct) * 2) * 64 + l) * 8;
        *(uint4*)(wbuf + base) = *(const uint4*)hi;
        *(uint4*)(wbuf + base + 64 * 8) = *(const uint4*)lo;
    }
}

// ---------------- main: GEMM-argmin, writes fidx + fflag ----------------
__global__ __launch_bounds__(THREADS, 2) void argmin_kernel(
    const float* __restrict__ keys, const float* __restrict__ vals,
    const unsigned short* __restrict__ wbuf, const float* __restrict__ c_sq,
    int* __restrict__ fidx_g, int* __restrict__ fflag_g) {
    __shared__ uint4 b_u4[2][2048];   // 64 KB: B dbuf, frag-major
    __shared__ uint4 a_u4[2][512];    // 16 KB: A dbuf, (rt*2+h)*64 + slot

    const int t = threadIdx.x;
    const int lane = t & 63;
    const int w = t >> 6;            // wave 0..3: code-quad ct = w*4+j
    const int tensor = blockIdx.y;
    const float* __restrict__ X = tensor ? vals : keys;
    const int row0 = blockIdx.x * MT;

    // A staging slot: thread t stages (rt = t>>6, slot = lane)
    const int s_row = row0 + (t >> 6) * 16 + (lane & 15);
    const int s_kq = (lane >> 4) * 8;
    const float* __restrict__ xrow = X + (size_t)s_row * H + s_kq;

    f32x4 acc[4][4];
    #pragma unroll
    for (int i = 0; i < 4; ++i)
        #pragma unroll
        for (int j = 0; j < 4; ++j) acc[i][j] = (f32x4){0.f, 0.f, 0.f, 0.f};

    // ---- prologue: stage step 0, prefetch step 1 ----
    {
        const float4 c0 = *(const float4*)(xrow);
        const float4 c1 = *(const float4*)(xrow + 4);
        float x[8] = {c0.x, c0.y, c0.z, c0.w, c1.x, c1.y, c1.z, c1.w};
        unsigned short hi[8], lo[8];
        #pragma unroll
        for (int j = 0; j < 8; ++j) {
            hi[j] = f2bf_rne(x[j]);
            lo[j] = f2bf_rne(x[j] - bf2f(hi[j]));
        }
        a_u4[0][((t >> 6) * 2 + 0) * 64 + lane] = *(const uint4*)hi;
        a_u4[0][((t >> 6) * 2 + 1) * 64 + lane] = *(const uint4*)lo;
        const char* gsrc = (const char*)wbuf + (size_t)w * 8192 + lane * 16;
        char* ldst = (char*)&b_u4[0][0] + w * 8192;
        #pragma unroll
        for (int c = 0; c < 8; ++c) gl_lds16(gsrc + c * 1024, ldst + c * 1024);
    }
    float4 nx0 = *(const float4*)(xrow + BK);
    float4 nx1 = *(const float4*)(xrow + BK + 4);
    __syncthreads();

    for (int s = 0; s < KSTEPS; ++s) {
        const int p = s & 1;
        if (s + 1 < KSTEPS) {
            // stage step s+1 into buffer p^1 (stale since end of step s-1)
            float x[8] = {nx0.x, nx0.y, nx0.z, nx0.w, nx1.x, nx1.y, nx1.z, nx1.w};
            unsigned short hi[8], lo[8];
            #pragma unroll
            for (int j = 0; j < 8; ++j) {
                hi[j] = f2bf_rne(x[j]);
                lo[j] = f2bf_rne(x[j] - bf2f(hi[j]));
            }
            a_u4[p ^ 1][((t >> 6) * 2 + 0) * 64 + lane] = *(const uint4*)hi;
            a_u4[p ^ 1][((t >> 6) * 2 + 1) * 64 + lane] = *(const uint4*)lo;
            const char* gsrc = (const char*)wbuf + (size_t)(s + 1) * 32768 + w * 8192 + lane * 16;
            char* ldst = (char*)&b_u4[p ^ 1][0] + w * 8192;
            #pragma unroll
            for (int c = 0; c < 8; ++c) gl_lds16(gsrc + c * 1024, ldst + c * 1024);
        }
        if (s + 2 < KSTEPS) {
            nx0 = *(const float4*)(xrow + (s + 2) * BK);
            nx1 = *(const float4*)(xrow + (s + 2) * BK + 4);
        }
        // compute on buffer p
        bf16x8 ah[4], al[4], bh[4], bl[4];
        #pragma unroll
        for (int i = 0; i < 4; ++i) {
            ah[i] = ((const bf16x8*)&a_u4[p][0])[(i * 2 + 0) * 64 + lane];
            al[i] = ((const bf16x8*)&a_u4[p][0])[(i * 2 + 1) * 64 + lane];
        }
        #pragma unroll
        for (int j = 0; j < 4; ++j) {
            const int ct = w * 4 + j;
            bh[j] = ((const bf16x8*)&b_u4[p][0])[(ct * 2 + 0) * 64 + lane];
            bl[j] = ((const bf16x8*)&b_u4[p][0])[(ct * 2 + 1) * 64 + lane];
        }
        #pragma unroll
        for (int i = 0; i < 4; ++i)
            #pragma unroll
            for (int j = 0; j < 4; ++j) {
                acc[i][j] = __builtin_amdgcn_mfma_f32_16x16x32_bf16(ah[i], bl[j], acc[i][j], 0, 0, 0);
                acc[i][j] = __builtin_amdgcn_mfma_f32_16x16x32_bf16(al[i], bh[j], acc[i][j], 0, 0, 0);
                acc[i][j] = __builtin_amdgcn_mfma_f32_16x16x32_bf16(ah[i], bh[j], acc[i][j], 0, 0, 0);
            }
        __syncthreads();
    }

    // ---- per-row argmin with best-2 tracking ----
    float csq[4];
    #pragma unroll
    for (int j = 0; j < 4; ++j) csq[j] = c_sq[w * 64 + j * 16 + (lane & 15)];

    float* rv = (float*)&a_u4[0][0];        // [64][4]
    int* ri = (int*)&a_u4[0][0] + 256;      // [64][4]
    float* r2 = (float*)&a_u4[0][0] + 512;  // [64][4]

    #pragma unroll
    for (int i = 0; i < 4; ++i) {
        #pragma unroll
        for (int r = 0; r < 4; ++r) {
            const int row = i * 16 + (lane >> 4) * 4 + r;
            float bv = csq[0] - 2.0f * acc[i][0][r];
            int bc = w * 64 + (lane & 15);
            float b2 = 3.4e38f;
            #pragma unroll
            for (int j = 1; j < 4; ++j) {
                const float v = csq[j] - 2.0f * acc[i][j][r];
                if (v < bv) { b2 = bv; bv = v; bc = w * 64 + j * 16 + (lane & 15); }
                else b2 = fminf(b2, v);
            }
            #pragma unroll
            for (int off = 1; off < 16; off <<= 1) {
                const float ov = __shfl_xor(bv, off);
                const int oc = __shfl_xor(bc, off);
                const float ov2 = __shfl_xor(b2, off);
                const float nb2 = fminf(fmaxf(bv, ov), fminf(b2, ov2));
                if (ov < bv || (ov == bv && oc < bc)) { bv = ov; bc = oc; }
                b2 = nb2;
            }
            if ((lane & 15) == 0) {
                rv[row * 4 + w] = bv;
                ri[row * 4 + w] = bc;
                r2[row * 4 + w] = b2;
            }
        }
    }
    __syncthreads();
    if (t < MT) {
        float bv = rv[t * 4];
        int bc = ri[t * 4];
        float b2 = r2[t * 4];
        #pragma unroll
        for (int g = 1; g < 4; ++g) {        // ascending wave = ascending codes
            const float v = rv[t * 4 + g];
            const int c = ri[t * 4 + g];
            const float v2 = r2[t * 4 + g];
            const float nb2 = fminf(fmaxf(bv, v), fminf(b2, v2));
            if (v < bv || (v == bv && c < bc)) { bv = v; bc = c; }
            b2 = nb2;
        }
        const size_t rowg = (size_t)tensor * (gridDim.x * MT) + row0 + t;
        fidx_g[rowg] = bc;
        fflag_g[rowg] = (b2 - bv < 0.15f) ? 1 : 0;
    }
}

// ---------------- exact fp64 recheck of flagged rows ----------------
__global__ __launch_bounds__(256) void recheck_kernel(
    const float* __restrict__ keys, const float* __restrict__ vals,
    const float* __restrict__ wt, const float* __restrict__ c_sq,
    const int* __restrict__ fflag_g, int* __restrict__ fidx_g) {
    __shared__ float xs[H];
    __shared__ unsigned long long smask;
    __shared__ double bvs[4];
    __shared__ int bcs[4];

    const int t = threadIdx.x;
    const int row0 = blockIdx.x * 64;
    if (t < 64) {
        const int f = fflag_g[row0 + t];
        const unsigned long long m = __ballot(f != 0);
        if (t == 0) smask = m;
    }
    __syncthreads();
    unsigned long long mask = smask;
    while (mask) {
        const int r = __ffsll((long long)mask) - 1;
        mask &= mask - 1;
        const int rowg = row0 + r;
        const int tensor = rowg >> 14;
        const float* __restrict__ X = (tensor ? vals : keys) + (size_t)(rowg & 16383) * H;
        ((float4*)xs)[t] = ((const float4*)X)[t];
        __syncthreads();
        double d = 0.0;
        #pragma unroll 8
        for (int k = 0; k < H; ++k)
            d = fma((double)xs[k], (double)wt[(size_t)k * NC + t], d);
        double bv = (double)c_sq[t] - 2.0 * d;
        int bc = t;
        #pragma unroll
        for (int off = 1; off < 64; off <<= 1) {
            const double ov = __shfl_xor(bv, off);
            const int oc = __shfl_xor(bc, off);
            if (ov < bv || (ov == bv && oc < bc)) { bv = ov; bc = oc; }
        }
        if ((t & 63) == 0) { bvs[t >> 6] = bv; bcs[t >> 6] = bc; }
        __syncthreads();
        if (t == 0) {
            double fbv = bvs[0];
            int fbc = bcs[0];
            #pragma unroll
            for (int g = 1; g < 4; ++g)
                if (bvs[g] < fbv || (bvs[g] == fbv && bcs[g] < fbc)) { fbv = bvs[g]; fbc = bcs[g]; }
            fidx_g[rowg] = fbc;
        }
        __syncthreads();
    }
}

// ---------------- gather ----------------
__global__ __launch_bounds__(256) void gather_kernel(
    const float* __restrict__ cb, const float* __restrict__ c_sq,
    const int* __restrict__ fidx_g, float* __restrict__ out) {
    const int t = threadIdx.x;
    const int row = blockIdx.x * 4 + (t >> 6);
    const int lane = t & 63;
    const int ci = fidx_g[row];
    const float m = (c_sq[ci] > 0.01f) ? 1.0f : 0.0f;
    const float4* __restrict__ src = (const float4*)(cb + (size_t)ci * H);
    float4* __restrict__ dst = (float4*)(out + (size_t)row * H);
    #pragma unroll
    for (int j = 0; j < 4; ++j) {
        float4 v = src[lane + 64 * j];
        v.x *= m; v.y *= m; v.z *= m; v.w *= m;
        dst[lane + 64 * j] = v;
    }
}

extern "C" void kernel_launch(void* const* d_in, const int* in_sizes, int n_in,
                              void* d_out, int out_size, void* d_ws, size_t ws_size,
                              hipStream_t stream) {
    const float* keys = (const float*)d_in[0];
    const float* vals = (const float*)d_in[1];
    const float* cb   = (const float*)d_in[2];
    float* out = (float*)d_out;

    // ws: c_sq[256] f32 | wt[256K] f32 | wbuf[512K] u16 | fidx[32K] | fflag[32K]
    float* c_sq = (float*)d_ws;
    float* wt = c_sq + NC;
    unsigned short* wbuf = (unsigned short*)(wt + (size_t)H * NC);
    int* fidx_g = (int*)(wbuf + (size_t)KSTEPS * 2048 * 8);
    int* fflag_g = fidx_g + 32768;

    const int rows = in_sizes[0] / H;  // 16384 per tensor

    prep_kernel<<<NC, 256, 0, stream>>>(cb, c_sq, wt);
    prep_frag_kernel<<<KSTEPS, 256, 0, stream>>>(cb, wbuf);
    dim3 g(rows / MT, 2);
    argmin_kernel<<<g, THREADS, 0, stream>>>(keys, vals, wbuf, c_sq, fidx_g, fflag_g);
    recheck_kernel<<<rows * 2 / 64, 256, 0, stream>>>(keys, vals, wt, c_sq, fflag_g, fidx_g);
    gather_kernel<<<rows * 2 / 4, 256, 0, stream>>>(cb, c_sq, fidx_g, out);
}